// Round 13
// baseline (180.698 us; speedup 1.0000x reference)
//
#include <hip/hip_runtime.h>

// MCA linear attention, fp32. B=8, C=64, H=W=160, P=8 heads, d=8, N=25600.
#define NPIX  25600
#define NB    8
#define NCH   100    // k1 pixel chunks per batch (256 px each)
#define CPX   256    // k1 chunk pixels (64 lanes x 4 px)
#define KCH   200    // k3 pixel chunks per batch (128 px each)
#define KPX   128    // k3 chunk pixels (64 lanes x 2 px)
#define EPSV  1e-6f

// workspace layout (float offsets)
#define WS_WKVT  0        // [8 h][64 c][16]  (8 wk rows, 8 wv rows, transposed)
#define WS_WQT   8192     // [8 h][64 c][8]
#define WS_BKV   12288    // [8 h][16]
#define WS_BQ    12416    // [8 h][8]
#define WS_PART  12480    // [64 bh][100 ch][72]  (contiguous 72 per chunk)
#define WS_G     473280   // [8 b][64 pm][64 o]
#define WS_KSE   506048   // [8 b][8 p][8 m]

__device__ __forceinline__ float softplus_(float x) {
  // hw v_exp/v_log path; for x>20, log(1+e^x)==x to fp32 precision
  return (x > 20.0f) ? x : __logf(1.0f + __expf(x));
}

// DPP wave64 sum: row_shr 1/2/4/8 then row_bcast:15 (rows 1,3) and
// row_bcast:31 (rows 2,3). Full sum lands in lane 63. old=0 makes masked /
// invalid lanes contribute 0 regardless of bound_ctrl interpretation.
template <int CTRL, int RMASK>
__device__ __forceinline__ float dpp_add(float x) {
  int y = __builtin_amdgcn_update_dpp(0, __float_as_int(x), CTRL, RMASK, 0xf, false);
  return x + __int_as_float(y);
}
__device__ __forceinline__ float wave_sum63(float x) {
  x = dpp_add<0x111, 0xf>(x);   // row_shr:1
  x = dpp_add<0x112, 0xf>(x);   // row_shr:2
  x = dpp_add<0x114, 0xf>(x);   // row_shr:4
  x = dpp_add<0x118, 0xf>(x);   // row_shr:8
  x = dpp_add<0x142, 0xa>(x);   // row_bcast:15 -> rows 1,3
  x = dpp_add<0x143, 0xc>(x);   // row_bcast:31 -> rows 2,3
  return x;                     // lane 63 holds the wave total
}

// ---------------- kernel 0: pack weights/biases transposed ----------------
__global__ void k0_pack(const float* __restrict__ wq_high, const float* __restrict__ bq_high,
                        const float* __restrict__ wq_low,  const float* __restrict__ bq_low,
                        const float* __restrict__ wk, const float* __restrict__ bk,
                        const float* __restrict__ wv, const float* __restrict__ bv,
                        float* __restrict__ ws) {
  const int tid = threadIdx.x;
  for (int e = tid; e < 8192; e += 256) {        // wkvT[h][c][j]
    int j = e & 15, c = (e >> 4) & 63, h = e >> 10, m = j & 7;
    float v = (j < 8) ? wk[(h * 8 + m) * 64 + c] : wv[(h * 8 + m) * 64 + c];
    ws[WS_WKVT + e] = v;
  }
  for (int e = tid; e < 4096; e += 256) {        // wqT[h][c][m]
    int m = e & 7, c = (e >> 3) & 63, h = e >> 9;
    float v = (h < 4) ? wq_high[(h * 8 + m) * 64 + c]
                      : wq_low[((h - 4) * 8 + m) * 64 + c];
    ws[WS_WQT + e] = v;
  }
  for (int e = tid; e < 128; e += 256) {         // bkv[h][j]
    int j = e & 15, h = e >> 4, m = j & 7;
    ws[WS_BKV + e] = (j < 8) ? bk[h * 8 + m] : bv[h * 8 + m];
  }
  for (int e = tid; e < 64; e += 256) {          // bq[h][m]
    int m = e & 7, h = e >> 3;
    ws[WS_BQ + e] = (h < 4) ? bq_high[h * 8 + m] : bq_low[(h - 4) * 8 + m];
  }
}

// ---------------- kernel 1: k,v -> per-chunk partial attn/ksum ----------------
// 256 threads = 4 waves; block (chunk, b, half) -> wave w = head half*4+w.
// Weights staged in LDS (16KB/block); in-loop weight reads are wave-uniform
// ds_read = free broadcast, pipelined deep in VGPRs (replaces the s_load
// stream whose ~2-deep SGPR pipelining was the measured 33-50% stall:
// R11 null [x->LDS] + R12 null [2x occupancy] isolated the scalar path).
// Lane owns 4 px (float4). Row-streaming + DPP reduce.
__global__ __attribute__((amdgpu_waves_per_eu(1, 8)))
void k1_kv(const float* __restrict__ low,
           const float* __restrict__ ws,
           float* __restrict__ part) {
  const int b = blockIdx.y >> 1, half = blockIdx.y & 1, chunk = blockIdx.x;
  const int tid = threadIdx.x, lane = tid & 63;
  const int wu = __builtin_amdgcn_readfirstlane(tid >> 6);
  __shared__ float wlds[4096];                   // [4 h][64 c][16] = 16 KB
  {
    const float4* wsrc = reinterpret_cast<const float4*>(ws + WS_WKVT + half * 4096);
    float4* wdst = reinterpret_cast<float4*>(wlds);
#pragma unroll
    for (int i = 0; i < 4; i++) wdst[tid + i * 256] = wsrc[tid + i * 256];
  }
  const float* lowb = low + (size_t)b * 64 * NPIX + chunk * CPX;
  const float* wt = wlds + wu * 1024;            // wave-uniform -> ds broadcast
  const float* bias = ws + WS_BKV + (half * 4 + wu) * 16;
  float ka[8][4], va[8][4];
#pragma unroll
  for (int m = 0; m < 8; m++) {
    float bkm = bias[m], bvm = bias[8 + m];
#pragma unroll
    for (int px = 0; px < 4; px++) { ka[m][px] = bkm; va[m][px] = bvm; }
  }
  __syncthreads();
#pragma unroll 8
  for (int c = 0; c < 64; c++) {
    float4 x = reinterpret_cast<const float4*>(lowb + (size_t)c * NPIX)[lane];
    const float* wr = wt + c * 16;
    float4 wk4 = reinterpret_cast<const float4*>(wr)[0];
    float4 wk8 = reinterpret_cast<const float4*>(wr)[1];
    float4 wv4 = reinterpret_cast<const float4*>(wr)[2];
    float4 wv8 = reinterpret_cast<const float4*>(wr)[3];
    const float wkm[8] = {wk4.x, wk4.y, wk4.z, wk4.w, wk8.x, wk8.y, wk8.z, wk8.w};
    const float wvm[8] = {wv4.x, wv4.y, wv4.z, wv4.w, wv8.x, wv8.y, wv8.z, wv8.w};
#pragma unroll
    for (int m = 0; m < 8; m++) {
      ka[m][0] = fmaf(wkm[m], x.x, ka[m][0]);
      ka[m][1] = fmaf(wkm[m], x.y, ka[m][1]);
      ka[m][2] = fmaf(wkm[m], x.z, ka[m][2]);
      ka[m][3] = fmaf(wkm[m], x.w, ka[m][3]);
      va[m][0] = fmaf(wvm[m], x.x, va[m][0]);
      va[m][1] = fmaf(wvm[m], x.y, va[m][1]);
      va[m][2] = fmaf(wvm[m], x.z, va[m][2]);
      va[m][3] = fmaf(wvm[m], x.w, va[m][3]);
    }
  }
#pragma unroll
  for (int m = 0; m < 8; m++)
#pragma unroll
    for (int px = 0; px < 4; px++) ka[m][px] = softplus_(ka[m][px]);
  float* pb = part + ((size_t)(b * 8 + half * 4 + wu) * NCH + chunk) * 72;
  // attn rows, streamed: products -> DPP reduce -> lane-63 store, row by row
#pragma unroll
  for (int m = 0; m < 8; m++) {
    float r[8];
#pragma unroll
    for (int c = 0; c < 8; c++) {
      float a = ka[m][0] * va[c][0];
      a = fmaf(ka[m][1], va[c][1], a);
      a = fmaf(ka[m][2], va[c][2], a);
      r[c] = fmaf(ka[m][3], va[c][3], a);
    }
#pragma unroll
    for (int c = 0; c < 8; c++) r[c] = wave_sum63(r[c]);
    if (lane == 63) {
      reinterpret_cast<float4*>(&pb[m * 8])[0] = make_float4(r[0], r[1], r[2], r[3]);
      reinterpret_cast<float4*>(&pb[m * 8])[1] = make_float4(r[4], r[5], r[6], r[7]);
    }
  }
  // ksum row
  {
    float r[8];
#pragma unroll
    for (int m = 0; m < 8; m++)
      r[m] = (ka[m][0] + ka[m][1]) + (ka[m][2] + ka[m][3]);
#pragma unroll
    for (int m = 0; m < 8; m++) r[m] = wave_sum63(r[m]);
    if (lane == 63) {
      reinterpret_cast<float4*>(&pb[64])[0] = make_float4(r[0], r[1], r[2], r[3]);
      reinterpret_cast<float4*>(&pb[64])[1] = make_float4(r[4], r[5], r[6], r[7]);
    }
  }
}

// ---------------- kernel 2: reduce partials, build G and ksumE ----------------
// 64 blocks (b*8+p) x 256 threads; chunk loop split 4-way across sub-waves.
__global__ void k2_g(const float* __restrict__ part, const float* __restrict__ wo,
                     float* __restrict__ ws) {
  const int b = blockIdx.x >> 3, p = blockIdx.x & 7;
  const int tid = threadIdx.x, lane = tid & 63, sub = tid >> 6;
  __shared__ float red[4][72];
  __shared__ float attnL[72];
  const float* src = part + (size_t)(b * 8 + p) * NCH * 72;
  float s0 = 0.0f, s1 = 0.0f;
  for (int ch = sub * (NCH / 4); ch < (sub + 1) * (NCH / 4); ch++) {
    s0 += src[ch * 72 + lane];
    if (lane < 8) s1 += src[ch * 72 + 64 + lane];
  }
  red[sub][lane] = s0;
  if (lane < 8) red[sub][64 + lane] = s1;
  __syncthreads();
  if (tid < 72) attnL[tid] = (red[0][tid] + red[1][tid]) + (red[2][tid] + red[3][tid]);
  __syncthreads();
  if (tid >= 64) {
    if (tid < 72) ws[WS_KSE + (b * 8 + p) * 8 + (tid - 64)] = attnL[tid] + EPSV;
    return;
  }
  const int o = tid;
  float wrow[8];
#pragma unroll
  for (int c = 0; c < 8; c++) wrow[c] = wo[o * 64 + p * 8 + c];
  float* Gp = ws + WS_G + (size_t)(b * 64 + p * 8) * 64;
#pragma unroll
  for (int m = 0; m < 8; m++) {
    float g = 0.0f;
#pragma unroll
    for (int c = 0; c < 8; c++) g = fmaf(attnL[m * 8 + c], wrow[c], g);
    Gp[m * 64 + o] = g;
  }
}

// ---------------- kernel 3: q, norm, fused out-projection ----------------
// 512 threads = 8 waves, lane owns 2 px (float2). ALL uniform operands staged
// in LDS: wq (16KB, phase A) + G (16KB, phase B) + qsL (32KB) = 64KB exactly.
// In-loop weight/G reads become wave-uniform ds broadcasts (replacing the
// per-iteration s_load streams). 2 blocks/CU by LDS -- harmless per R12's
// occupancy-null result.
__global__ __attribute__((amdgpu_waves_per_eu(1, 8)))
void k3_main(const float* __restrict__ high,
             const float* __restrict__ low,
             const float* __restrict__ ws,
             const float* __restrict__ bo,
             float* __restrict__ out) {
  const int b = blockIdx.y, chunk = blockIdx.x;
  const int tid = threadIdx.x, lane = tid & 63;
  const int wu = __builtin_amdgcn_readfirstlane(tid >> 6);
  __shared__ float qsL[64 * KPX];                // 32 KB [64 pm][128 px]
  __shared__ float wqL[4096];                    // 16 KB [8 h][64 c][8]
  __shared__ float GL[4096];                     // 16 KB [64 pm][64 o]
  {
    const float4* ws1 = reinterpret_cast<const float4*>(ws + WS_WQT);
    const float4* ws2 = reinterpret_cast<const float4*>(ws + WS_G + (size_t)b * 4096);
    float4* d1 = reinterpret_cast<float4*>(wqL);
    float4* d2 = reinterpret_cast<float4*>(GL);
#pragma unroll
    for (int i = 0; i < 2; i++) {
      d1[tid + i * 512] = ws1[tid + i * 512];
      d2[tid + i * 512] = ws2[tid + i * 512];
    }
  }
  const float* srcb = ((wu < 4) ? high : low) + (size_t)b * 64 * NPIX + chunk * KPX;
  const float* wq  = wqL + wu * 512;             // wave-uniform -> ds broadcast
  const float* bq  = ws + WS_BQ + wu * 8;
  const float* kse = ws + WS_KSE + (b * 8 + wu) * 8;
  float qa[8][2];
#pragma unroll
  for (int m = 0; m < 8; m++) { qa[m][0] = bq[m]; qa[m][1] = bq[m]; }
  __syncthreads();
#pragma unroll 8
  for (int c = 0; c < 64; c++) {
    float2 x = reinterpret_cast<const float2*>(srcb + (size_t)c * NPIX)[lane];
    const float* wr = wq + c * 8;
    float4 w4 = reinterpret_cast<const float4*>(wr)[0];
    float4 w8 = reinterpret_cast<const float4*>(wr)[1];
    const float wm[8] = {w4.x, w4.y, w4.z, w4.w, w8.x, w8.y, w8.z, w8.w};
#pragma unroll
    for (int m = 0; m < 8; m++) {
      qa[m][0] = fmaf(wm[m], x.x, qa[m][0]);
      qa[m][1] = fmaf(wm[m], x.y, qa[m][1]);
    }
  }
  float s0 = 0.0f, s1 = 0.0f;
#pragma unroll
  for (int m = 0; m < 8; m++) {
    float km = kse[m];
    qa[m][0] = softplus_(qa[m][0]);
    qa[m][1] = softplus_(qa[m][1]);
    s0 = fmaf(qa[m][0], km, s0);
    s1 = fmaf(qa[m][1], km, s1);
  }
  const float r0 = 1.0f / s0, r1 = 1.0f / s1;
#pragma unroll
  for (int m = 0; m < 8; m++) {
    reinterpret_cast<float2*>(&qsL[(wu * 8 + m) * KPX])[lane] =
        make_float2(qa[m][0] * r0, qa[m][1] * r1);
  }
  __syncthreads();
  float acc[8][2];
#pragma unroll
  for (int j = 0; j < 8; j++) { acc[j][0] = bo[wu * 8 + j]; acc[j][1] = acc[j][0]; }
#pragma unroll 8
  for (int pm = 0; pm < 64; pm++) {
    float2 qv = reinterpret_cast<const float2*>(&qsL[pm * KPX])[lane];
    const float* gr = GL + pm * 64 + wu * 8;     // wave-uniform -> ds broadcast
    float4 g4 = reinterpret_cast<const float4*>(gr)[0];
    float4 g8 = reinterpret_cast<const float4*>(gr)[1];
    const float gm[8] = {g4.x, g4.y, g4.z, g4.w, g8.x, g8.y, g8.z, g8.w};
#pragma unroll
    for (int j = 0; j < 8; j++) {
      acc[j][0] = fmaf(gm[j], qv.x, acc[j][0]);
      acc[j][1] = fmaf(gm[j], qv.y, acc[j][1]);
    }
  }
  float* ob = out + (size_t)(b * 64 + wu * 8) * NPIX + chunk * KPX;
#pragma unroll
  for (int j = 0; j < 8; j++) {
    reinterpret_cast<float2*>(ob + (size_t)j * NPIX)[lane] =
        make_float2(acc[j][0], acc[j][1]);
  }
}

extern "C" void kernel_launch(void* const* d_in, const int* in_sizes, int n_in,
                              void* d_out, int out_size, void* d_ws, size_t ws_size,
                              hipStream_t stream) {
  const float* high    = (const float*)d_in[0];
  const float* low     = (const float*)d_in[1];
  const float* wq_high = (const float*)d_in[2];
  const float* bq_high = (const float*)d_in[3];
  const float* wq_low  = (const float*)d_in[4];
  const float* bq_low  = (const float*)d_in[5];
  const float* wk      = (const float*)d_in[6];
  const float* bk      = (const float*)d_in[7];
  const float* wv      = (const float*)d_in[8];
  const float* bv      = (const float*)d_in[9];
  const float* wo      = (const float*)d_in[10];
  const float* bo      = (const float*)d_in[11];
  float* ws  = (float*)d_ws;
  float* out = (float*)d_out;

  k0_pack<<<1, 256, 0, stream>>>(wq_high, bq_high, wq_low, bq_low, wk, bk, wv, bv, ws);
  dim3 grid1(NCH, NB * 2);
  k1_kv<<<grid1, 256, 0, stream>>>(low, ws, ws + WS_PART);
  k2_g<<<64, 256, 0, stream>>>(ws + WS_PART, wo, ws);
  dim3 grid3(KCH, NB);
  k3_main<<<grid3, 512, 0, stream>>>(high, low, ws, bo, out);
}

// Round 14
// 156.377 us; speedup vs baseline: 1.1555x; 1.1555x over previous
//
#include <hip/hip_runtime.h>

// MCA linear attention, fp32. B=8, C=64, H=W=160, P=8 heads, d=8, N=25600.
#define NPIX  25600
#define NB    8
#define NCH   100    // k1 pixel chunks per batch (256 px each)
#define CPX   256    // k1 chunk pixels
#define KCH   200    // k3 pixel chunks per batch (128 px each)
#define KPX   128    // k3 chunk pixels (64 lanes x 2 px)
#define EPSV  1e-6f

// workspace layout (float offsets)
#define WS_WKVT  0        // [8 h][64 c][16]  (8 wk rows, 8 wv rows, transposed)
#define WS_WQT   8192     // [8 h][64 c][8]
#define WS_BKV   12288    // [8 h][16]
#define WS_BQ    12416    // [8 h][8]
#define WS_PART  12480    // [64 bh][100 ch][72]  (contiguous 72 per chunk)
#define WS_G     473280   // [8 b][64 pm][64 o]
#define WS_KSE   506048   // [8 b][8 p][8 m]

__device__ __forceinline__ float softplus_(float x) {
  // hw v_exp/v_log path; for x>20, log(1+e^x)==x to fp32 precision
  return (x > 20.0f) ? x : __logf(1.0f + __expf(x));
}

// DPP wave64 sum: row_shr 1/2/4/8 then row_bcast:15 (rows 1,3) and
// row_bcast:31 (rows 2,3). Full sum lands in lane 63. old=0 makes masked /
// invalid lanes contribute 0 regardless of bound_ctrl interpretation.
template <int CTRL, int RMASK>
__device__ __forceinline__ float dpp_add(float x) {
  int y = __builtin_amdgcn_update_dpp(0, __float_as_int(x), CTRL, RMASK, 0xf, false);
  return x + __int_as_float(y);
}
__device__ __forceinline__ float wave_sum63(float x) {
  x = dpp_add<0x111, 0xf>(x);   // row_shr:1
  x = dpp_add<0x112, 0xf>(x);   // row_shr:2
  x = dpp_add<0x114, 0xf>(x);   // row_shr:4
  x = dpp_add<0x118, 0xf>(x);   // row_shr:8
  x = dpp_add<0x142, 0xa>(x);   // row_bcast:15 -> rows 1,3
  x = dpp_add<0x143, 0xc>(x);   // row_bcast:31 -> rows 2,3
  return x;                     // lane 63 holds the wave total
}

// ---------------- kernel 0: pack weights/biases transposed ----------------
__global__ void k0_pack(const float* __restrict__ wq_high, const float* __restrict__ bq_high,
                        const float* __restrict__ wq_low,  const float* __restrict__ bq_low,
                        const float* __restrict__ wk, const float* __restrict__ bk,
                        const float* __restrict__ wv, const float* __restrict__ bv,
                        float* __restrict__ ws) {
  const int tid = threadIdx.x;
  for (int e = tid; e < 8192; e += 256) {        // wkvT[h][c][j]
    int j = e & 15, c = (e >> 4) & 63, h = e >> 10, m = j & 7;
    float v = (j < 8) ? wk[(h * 8 + m) * 64 + c] : wv[(h * 8 + m) * 64 + c];
    ws[WS_WKVT + e] = v;
  }
  for (int e = tid; e < 4096; e += 256) {        // wqT[h][c][m]
    int m = e & 7, c = (e >> 3) & 63, h = e >> 9;
    float v = (h < 4) ? wq_high[(h * 8 + m) * 64 + c]
                      : wq_low[((h - 4) * 8 + m) * 64 + c];
    ws[WS_WQT + e] = v;
  }
  for (int e = tid; e < 128; e += 256) {         // bkv[h][j]
    int j = e & 15, h = e >> 4, m = j & 7;
    ws[WS_BKV + e] = (j < 8) ? bk[h * 8 + m] : bv[h * 8 + m];
  }
  for (int e = tid; e < 64; e += 256) {          // bq[h][m]
    int m = e & 7, h = e >> 3;
    ws[WS_BQ + e] = (h < 4) ? bq_high[h * 8 + m] : bq_low[(h - 4) * 8 + m];
  }
}

// ---------------- kernel 1: k,v -> per-chunk partial attn/ksum ----------------
// TLP fix: 512 thr = 8 waves = 4 heads x {k-wave, v-wave}. Each wave does
// HALF the old per-wave conv (8 rows x 256 px = 2048 FMA) -> 12800 total
// waves (2x R12) at unchanged total instruction count. softplus'd k and v
// exchanged via 32KB LDS (two 128-px halves -> 4 blocks/CU, 8 waves/SIMD
// residency cap). attn rows 0-3 on k-wave, 4-7 on v-wave; per-lane products
// accumulate across halves so the DPP reduce runs once (amortization kept).
__global__ __attribute__((amdgpu_waves_per_eu(1, 8)))
void k1_kv(const float* __restrict__ low,
           const float* __restrict__ ws,
           float* __restrict__ part) {
  const int b = blockIdx.y >> 1, hg = blockIdx.y & 1, chunk = blockIdx.x;
  const int tid = threadIdx.x, lane = tid & 63;
  const int wu = __builtin_amdgcn_readfirstlane(tid >> 6);
  const int hl = wu >> 1, role = wu & 1;         // local head 0-3, 0=k 1=v
  const int h = hg * 4 + hl;
  __shared__ float kvL[4 * 16 * 128];            // [4 h][16 ch][128 px] 32 KB
  const float* lowb = low + (size_t)b * 64 * NPIX + chunk * CPX;
  const float* wt = ws + WS_WKVT + h * 1024 + role * 8;   // wave-uniform
  const float* bias = ws + WS_BKV + h * 16 + role * 8;
  float racc[4][8];                              // attn partial products
  float ks[8];                                   // ksum partials (k-wave)
#pragma unroll
  for (int m = 0; m < 4; m++)
#pragma unroll
    for (int c = 0; c < 8; c++) racc[m][c] = 0.0f;
#pragma unroll
  for (int m = 0; m < 8; m++) ks[m] = 0.0f;
  float bias_[8];
#pragma unroll
  for (int m = 0; m < 8; m++) bias_[m] = bias[m];

#pragma unroll
  for (int t = 0; t < 2; t++) {                  // two 128-px halves
    const float* xb = lowb + t * 128;
    float a[8][2];
#pragma unroll
    for (int m = 0; m < 8; m++) { a[m][0] = bias_[m]; a[m][1] = bias_[m]; }
#pragma unroll 4
    for (int c = 0; c < 64; c++) {
      float2 x = reinterpret_cast<const float2*>(xb + (size_t)c * NPIX)[lane];
      const float* wr = wt + c * 16;
#pragma unroll
      for (int m = 0; m < 8; m++) {
        float w = wr[m];
        a[m][0] = fmaf(w, x.x, a[m][0]);
        a[m][1] = fmaf(w, x.y, a[m][1]);
      }
    }
    if (role == 0) {
#pragma unroll
      for (int m = 0; m < 8; m++) {
        a[m][0] = softplus_(a[m][0]);
        a[m][1] = softplus_(a[m][1]);
        ks[m] += a[m][0] + a[m][1];
      }
    }
    // exchange through LDS
#pragma unroll
    for (int m = 0; m < 8; m++)
      reinterpret_cast<float2*>(&kvL[(hl * 16 + role * 8 + m) * 128])[lane] =
          make_float2(a[m][0], a[m][1]);
    __syncthreads();
    if (role == 0) {
      // own a = k rows 0-7; read v rows 0-7; do attn rows 0-3
#pragma unroll
      for (int c = 0; c < 8; c++) {
        float2 v = reinterpret_cast<const float2*>(&kvL[(hl * 16 + 8 + c) * 128])[lane];
#pragma unroll
        for (int m = 0; m < 4; m++)
          racc[m][c] = fmaf(a[m][1], v.y, fmaf(a[m][0], v.x, racc[m][c]));
      }
    } else {
      // own a = v rows 0-7; read softplus'd k rows 4-7; do attn rows 4-7
#pragma unroll
      for (int m = 0; m < 4; m++) {
        float2 k = reinterpret_cast<const float2*>(&kvL[(hl * 16 + 4 + m) * 128])[lane];
#pragma unroll
        for (int c = 0; c < 8; c++)
          racc[m][c] = fmaf(k.y, a[c][1], fmaf(k.x, a[c][0], racc[m][c]));
      }
    }
    __syncthreads();                             // protect kvL reuse next half
  }
  // DPP reduce (once) + store
  float* pb = part + ((size_t)(b * 8 + h) * NCH + chunk) * 72;
#pragma unroll
  for (int m = 0; m < 4; m++) {
#pragma unroll
    for (int c = 0; c < 8; c++) racc[m][c] = wave_sum63(racc[m][c]);
    if (lane == 63) {
      const int row = role == 0 ? m : 4 + m;
      reinterpret_cast<float4*>(&pb[row * 8])[0] =
          make_float4(racc[m][0], racc[m][1], racc[m][2], racc[m][3]);
      reinterpret_cast<float4*>(&pb[row * 8])[1] =
          make_float4(racc[m][4], racc[m][5], racc[m][6], racc[m][7]);
    }
  }
  if (role == 0) {
#pragma unroll
    for (int m = 0; m < 8; m++) ks[m] = wave_sum63(ks[m]);
    if (lane == 63) {
      reinterpret_cast<float4*>(&pb[64])[0] = make_float4(ks[0], ks[1], ks[2], ks[3]);
      reinterpret_cast<float4*>(&pb[64])[1] = make_float4(ks[4], ks[5], ks[6], ks[7]);
    }
  }
}

// ---------------- kernel 2: reduce partials, build G and ksumE ----------------
// 64 blocks (b*8+p) x 256 threads; chunk loop split 4-way across sub-waves.
__global__ void k2_g(const float* __restrict__ part, const float* __restrict__ wo,
                     float* __restrict__ ws) {
  const int b = blockIdx.x >> 3, p = blockIdx.x & 7;
  const int tid = threadIdx.x, lane = tid & 63, sub = tid >> 6;
  __shared__ float red[4][72];
  __shared__ float attnL[72];
  const float* src = part + (size_t)(b * 8 + p) * NCH * 72;
  float s0 = 0.0f, s1 = 0.0f;
  for (int ch = sub * (NCH / 4); ch < (sub + 1) * (NCH / 4); ch++) {
    s0 += src[ch * 72 + lane];
    if (lane < 8) s1 += src[ch * 72 + 64 + lane];
  }
  red[sub][lane] = s0;
  if (lane < 8) red[sub][64 + lane] = s1;
  __syncthreads();
  if (tid < 72) attnL[tid] = (red[0][tid] + red[1][tid]) + (red[2][tid] + red[3][tid]);
  __syncthreads();
  if (tid >= 64) {
    if (tid < 72) ws[WS_KSE + (b * 8 + p) * 8 + (tid - 64)] = attnL[tid] + EPSV;
    return;
  }
  const int o = tid;
  float wrow[8];
#pragma unroll
  for (int c = 0; c < 8; c++) wrow[c] = wo[o * 64 + p * 8 + c];
  float* Gp = ws + WS_G + (size_t)(b * 64 + p * 8) * 64;
#pragma unroll
  for (int m = 0; m < 8; m++) {
    float g = 0.0f;
#pragma unroll
    for (int c = 0; c < 8; c++) g = fmaf(attnL[m * 8 + c], wrow[c], g);
    Gp[m * 64 + o] = g;
  }
}

// ---------------- kernel 3: q, norm, fused out-projection ----------------
// R12's best k3: 512 thr = 8 waves, lane owns 2 px (float2), qsL 32 KB ->
// 4 blocks/CU. Phase A: wave w -> qs for head w. Phase B: wave w -> output
// channels [8w,8w+8) (G via wave-uniform s_loads).
__global__ __attribute__((amdgpu_waves_per_eu(1, 8)))
void k3_main(const float* __restrict__ high,
             const float* __restrict__ low,
             const float* __restrict__ ws,
             const float* __restrict__ bo,
             float* __restrict__ out) {
  const int b = blockIdx.y, chunk = blockIdx.x;
  const int tid = threadIdx.x, lane = tid & 63;
  const int wu = __builtin_amdgcn_readfirstlane(tid >> 6);
  __shared__ float qsL[64 * KPX];                // [64 pm][128 px] = 32 KB
  const float* srcb = ((wu < 4) ? high : low) + (size_t)b * 64 * NPIX + chunk * KPX;
  const float* wq  = ws + WS_WQT + wu * 512;
  const float* bq  = ws + WS_BQ + wu * 8;
  const float* kse = ws + WS_KSE + (b * 8 + wu) * 8;
  const float* Gb  = ws + WS_G + (size_t)b * 4096 + wu * 8;
  float qa[8][2];
#pragma unroll
  for (int m = 0; m < 8; m++) { qa[m][0] = bq[m]; qa[m][1] = bq[m]; }
#pragma unroll 8
  for (int c = 0; c < 64; c++) {
    float2 x = reinterpret_cast<const float2*>(srcb + (size_t)c * NPIX)[lane];
    const float* wr = wq + c * 8;
#pragma unroll
    for (int m = 0; m < 8; m++) {
      float w = wr[m];
      qa[m][0] = fmaf(w, x.x, qa[m][0]);
      qa[m][1] = fmaf(w, x.y, qa[m][1]);
    }
  }
  float s0 = 0.0f, s1 = 0.0f;
#pragma unroll
  for (int m = 0; m < 8; m++) {
    float km = kse[m];
    qa[m][0] = softplus_(qa[m][0]);
    qa[m][1] = softplus_(qa[m][1]);
    s0 = fmaf(qa[m][0], km, s0);
    s1 = fmaf(qa[m][1], km, s1);
  }
  const float r0 = 1.0f / s0, r1 = 1.0f / s1;
#pragma unroll
  for (int m = 0; m < 8; m++) {
    reinterpret_cast<float2*>(&qsL[(wu * 8 + m) * KPX])[lane] =
        make_float2(qa[m][0] * r0, qa[m][1] * r1);
  }
  __syncthreads();
  float acc[8][2];
#pragma unroll
  for (int j = 0; j < 8; j++) { acc[j][0] = bo[wu * 8 + j]; acc[j][1] = acc[j][0]; }
#pragma unroll 8
  for (int pm = 0; pm < 64; pm++) {
    float2 qv = reinterpret_cast<const float2*>(&qsL[pm * KPX])[lane];
    const float* gr = Gb + pm * 64;              // wave-uniform -> s_load
#pragma unroll
    for (int j = 0; j < 8; j++) {
      float g = gr[j];
      acc[j][0] = fmaf(g, qv.x, acc[j][0]);
      acc[j][1] = fmaf(g, qv.y, acc[j][1]);
    }
  }
  float* ob = out + (size_t)(b * 64 + wu * 8) * NPIX + chunk * KPX;
#pragma unroll
  for (int j = 0; j < 8; j++) {
    reinterpret_cast<float2*>(ob + (size_t)j * NPIX)[lane] =
        make_float2(acc[j][0], acc[j][1]);
  }
}

extern "C" void kernel_launch(void* const* d_in, const int* in_sizes, int n_in,
                              void* d_out, int out_size, void* d_ws, size_t ws_size,
                              hipStream_t stream) {
  const float* high    = (const float*)d_in[0];
  const float* low     = (const float*)d_in[1];
  const float* wq_high = (const float*)d_in[2];
  const float* bq_high = (const float*)d_in[3];
  const float* wq_low  = (const float*)d_in[4];
  const float* bq_low  = (const float*)d_in[5];
  const float* wk      = (const float*)d_in[6];
  const float* bk      = (const float*)d_in[7];
  const float* wv      = (const float*)d_in[8];
  const float* bv      = (const float*)d_in[9];
  const float* wo      = (const float*)d_in[10];
  const float* bo      = (const float*)d_in[11];
  float* ws  = (float*)d_ws;
  float* out = (float*)d_out;

  k0_pack<<<1, 256, 0, stream>>>(wq_high, bq_high, wq_low, bq_low, wk, bk, wv, bv, ws);
  dim3 grid1(NCH, NB * 2);
  k1_kv<<<grid1, 512, 0, stream>>>(low, ws, ws + WS_PART);
  k2_g<<<64, 256, 0, stream>>>(ws + WS_PART, wo, ws);
  dim3 grid3(KCH, NB);
  k3_main<<<grid3, 512, 0, stream>>>(high, low, ws, bo, out);
}

// Round 15
// 130.956 us; speedup vs baseline: 1.3798x; 1.1941x over previous
//
#include <hip/hip_runtime.h>

// MCA linear attention, fp32. B=8, C=64, H=W=160, P=8 heads, d=8, N=25600.
#define NPIX  25600
#define NB    8
#define NCH   100    // k1 pixel chunks per batch (256 px each)
#define CPX   256    // k1 chunk pixels (64 lanes x 4 px)
#define KCH   200    // k3 pixel chunks per batch (128 px each)
#define KPX   128    // k3 chunk pixels (64 lanes x 2 px)
#define EPSV  1e-6f

// workspace layout (float offsets)
#define WS_WKVT  0        // [8 h][64 c][16]  (8 wk rows, 8 wv rows, transposed)
#define WS_WQT   8192     // [8 h][64 c][8]
#define WS_BKV   12288    // [8 h][16]
#define WS_BQ    12416    // [8 h][8]
#define WS_PART  12480    // [64 bh][100 ch][72]  (contiguous 72 per chunk)
#define WS_G     473280   // [8 b][64 pm][64 o]
#define WS_KSE   506048   // [8 b][8 p][8 m]

__device__ __forceinline__ float softplus_(float x) {
  // hw v_exp/v_log path; for x>20, log(1+e^x)==x to fp32 precision
  return (x > 20.0f) ? x : __logf(1.0f + __expf(x));
}

// DPP wave64 sum: row_shr 1/2/4/8 then row_bcast:15 (rows 1,3) and
// row_bcast:31 (rows 2,3). Full sum lands in lane 63. old=0 makes masked /
// invalid lanes contribute 0 regardless of bound_ctrl interpretation.
template <int CTRL, int RMASK>
__device__ __forceinline__ float dpp_add(float x) {
  int y = __builtin_amdgcn_update_dpp(0, __float_as_int(x), CTRL, RMASK, 0xf, false);
  return x + __int_as_float(y);
}
__device__ __forceinline__ float wave_sum63(float x) {
  x = dpp_add<0x111, 0xf>(x);   // row_shr:1
  x = dpp_add<0x112, 0xf>(x);   // row_shr:2
  x = dpp_add<0x114, 0xf>(x);   // row_shr:4
  x = dpp_add<0x118, 0xf>(x);   // row_shr:8
  x = dpp_add<0x142, 0xa>(x);   // row_bcast:15 -> rows 1,3
  x = dpp_add<0x143, 0xc>(x);   // row_bcast:31 -> rows 2,3
  return x;                     // lane 63 holds the wave total
}

// ---------------- kernel 0: pack weights/biases transposed ----------------
__global__ void k0_pack(const float* __restrict__ wq_high, const float* __restrict__ bq_high,
                        const float* __restrict__ wq_low,  const float* __restrict__ bq_low,
                        const float* __restrict__ wk, const float* __restrict__ bk,
                        const float* __restrict__ wv, const float* __restrict__ bv,
                        float* __restrict__ ws) {
  const int tid = threadIdx.x;
  for (int e = tid; e < 8192; e += 256) {        // wkvT[h][c][j]
    int j = e & 15, c = (e >> 4) & 63, h = e >> 10, m = j & 7;
    float v = (j < 8) ? wk[(h * 8 + m) * 64 + c] : wv[(h * 8 + m) * 64 + c];
    ws[WS_WKVT + e] = v;
  }
  for (int e = tid; e < 4096; e += 256) {        // wqT[h][c][m]
    int m = e & 7, c = (e >> 3) & 63, h = e >> 9;
    float v = (h < 4) ? wq_high[(h * 8 + m) * 64 + c]
                      : wq_low[((h - 4) * 8 + m) * 64 + c];
    ws[WS_WQT + e] = v;
  }
  for (int e = tid; e < 128; e += 256) {         // bkv[h][j]
    int j = e & 15, h = e >> 4, m = j & 7;
    ws[WS_BKV + e] = (j < 8) ? bk[h * 8 + m] : bv[h * 8 + m];
  }
  for (int e = tid; e < 64; e += 256) {          // bq[h][m]
    int m = e & 7, h = e >> 3;
    ws[WS_BQ + e] = (h < 4) ? bq_high[h * 8 + m] : bq_low[(h - 4) * 8 + m];
  }
}

// ---------------- kernel 1: k,v -> per-chunk partial attn/ksum ----------------
// Measured-best structure (R9/R12, 65 us): 256 threads = 4 waves; block
// (chunk, b, half) -> wave w = head half*4+w. Lane owns 4 px (float4 loads).
// Weights via wave-uniform s_loads; row-streaming + DPP reduce; scalar fmaf.
// Perturbations all measured worse: 8-wave blocks (74), LDS weights (121),
// LDS x (74), k/v wave split (101), pk_fma (67), launch_bounds caps (spill).
__global__ __attribute__((amdgpu_waves_per_eu(1, 8)))
void k1_kv(const float* __restrict__ low,
           const float* __restrict__ ws,
           float* __restrict__ part) {
  const int b = blockIdx.y >> 1, half = blockIdx.y & 1, chunk = blockIdx.x;
  const int tid = threadIdx.x, lane = tid & 63;
  const int wu = __builtin_amdgcn_readfirstlane(half * 4 + (tid >> 6));
  const float* lowb = low + (size_t)b * 64 * NPIX + chunk * CPX;
  const float* wt = ws + WS_WKVT + wu * 1024;    // wave-uniform -> s_load
  const float* bias = ws + WS_BKV + wu * 16;
  float ka[8][4], va[8][4];
#pragma unroll
  for (int m = 0; m < 8; m++) {
    float bkm = bias[m], bvm = bias[8 + m];
#pragma unroll
    for (int px = 0; px < 4; px++) { ka[m][px] = bkm; va[m][px] = bvm; }
  }
#pragma unroll 8
  for (int c = 0; c < 64; c++) {
    float4 x = reinterpret_cast<const float4*>(lowb + (size_t)c * NPIX)[lane];
    const float* wr = wt + c * 16;
#pragma unroll
    for (int m = 0; m < 8; m++) {
      float wkm = wr[m], wvm = wr[8 + m];
      ka[m][0] = fmaf(wkm, x.x, ka[m][0]);
      ka[m][1] = fmaf(wkm, x.y, ka[m][1]);
      ka[m][2] = fmaf(wkm, x.z, ka[m][2]);
      ka[m][3] = fmaf(wkm, x.w, ka[m][3]);
      va[m][0] = fmaf(wvm, x.x, va[m][0]);
      va[m][1] = fmaf(wvm, x.y, va[m][1]);
      va[m][2] = fmaf(wvm, x.z, va[m][2]);
      va[m][3] = fmaf(wvm, x.w, va[m][3]);
    }
  }
#pragma unroll
  for (int m = 0; m < 8; m++)
#pragma unroll
    for (int px = 0; px < 4; px++) ka[m][px] = softplus_(ka[m][px]);
  float* pb = part + ((size_t)(b * 8 + wu) * NCH + chunk) * 72;
  // attn rows, streamed: products -> DPP reduce -> lane-63 store, row by row
#pragma unroll
  for (int m = 0; m < 8; m++) {
    float r[8];
#pragma unroll
    for (int c = 0; c < 8; c++) {
      float a = ka[m][0] * va[c][0];
      a = fmaf(ka[m][1], va[c][1], a);
      a = fmaf(ka[m][2], va[c][2], a);
      r[c] = fmaf(ka[m][3], va[c][3], a);
    }
#pragma unroll
    for (int c = 0; c < 8; c++) r[c] = wave_sum63(r[c]);
    if (lane == 63) {
      reinterpret_cast<float4*>(&pb[m * 8])[0] = make_float4(r[0], r[1], r[2], r[3]);
      reinterpret_cast<float4*>(&pb[m * 8])[1] = make_float4(r[4], r[5], r[6], r[7]);
    }
  }
  // ksum row
  {
    float r[8];
#pragma unroll
    for (int m = 0; m < 8; m++)
      r[m] = (ka[m][0] + ka[m][1]) + (ka[m][2] + ka[m][3]);
#pragma unroll
    for (int m = 0; m < 8; m++) r[m] = wave_sum63(r[m]);
    if (lane == 63) {
      reinterpret_cast<float4*>(&pb[64])[0] = make_float4(r[0], r[1], r[2], r[3]);
      reinterpret_cast<float4*>(&pb[64])[1] = make_float4(r[4], r[5], r[6], r[7]);
    }
  }
}

// ---------------- kernel 2: reduce partials, build G and ksumE ----------------
// 64 blocks (b*8+p) x 256 threads; chunk loop split 4-way across sub-waves.
__global__ void k2_g(const float* __restrict__ part, const float* __restrict__ wo,
                     float* __restrict__ ws) {
  const int b = blockIdx.x >> 3, p = blockIdx.x & 7;
  const int tid = threadIdx.x, lane = tid & 63, sub = tid >> 6;
  __shared__ float red[4][72];
  __shared__ float attnL[72];
  const float* src = part + (size_t)(b * 8 + p) * NCH * 72;
  float s0 = 0.0f, s1 = 0.0f;
  for (int ch = sub * (NCH / 4); ch < (sub + 1) * (NCH / 4); ch++) {
    s0 += src[ch * 72 + lane];
    if (lane < 8) s1 += src[ch * 72 + 64 + lane];
  }
  red[sub][lane] = s0;
  if (lane < 8) red[sub][64 + lane] = s1;
  __syncthreads();
  if (tid < 72) attnL[tid] = (red[0][tid] + red[1][tid]) + (red[2][tid] + red[3][tid]);
  __syncthreads();
  if (tid >= 64) {
    if (tid < 72) ws[WS_KSE + (b * 8 + p) * 8 + (tid - 64)] = attnL[tid] + EPSV;
    return;
  }
  const int o = tid;
  float wrow[8];
#pragma unroll
  for (int c = 0; c < 8; c++) wrow[c] = wo[o * 64 + p * 8 + c];
  float* Gp = ws + WS_G + (size_t)(b * 64 + p * 8) * 64;
#pragma unroll
  for (int m = 0; m < 8; m++) {
    float g = 0.0f;
#pragma unroll
    for (int c = 0; c < 8; c++) g = fmaf(attnL[m * 8 + c], wrow[c], g);
    Gp[m * 64 + o] = g;
  }
}

// ---------------- kernel 3: q, norm, fused out-projection ----------------
// 512 threads = 8 waves, lane owns 2 px (float2). qsL 32 KB -> 4 blocks/CU.
// Phase A: wave w -> qs for head w. Phase B: wave w -> output channels
// [8w,8w+8) (G via wave-uniform s_loads). NO waves_per_eu attribute: R12's
// attr variant showed VGPR_Count=24 (AGPR packing); R7's attr-free 2px k3
// implied ~62 us. Testing the attr as the last untested k3 knob.
__global__ void k3_main(const float* __restrict__ high,
                        const float* __restrict__ low,
                        const float* __restrict__ ws,
                        const float* __restrict__ bo,
                        float* __restrict__ out) {
  const int b = blockIdx.y, chunk = blockIdx.x;
  const int tid = threadIdx.x, lane = tid & 63;
  const int wu = __builtin_amdgcn_readfirstlane(tid >> 6);
  __shared__ float qsL[64 * KPX];                // [64 pm][128 px] = 32 KB
  const float* srcb = ((wu < 4) ? high : low) + (size_t)b * 64 * NPIX + chunk * KPX;
  const float* wq  = ws + WS_WQT + wu * 512;
  const float* bq  = ws + WS_BQ + wu * 8;
  const float* kse = ws + WS_KSE + (b * 8 + wu) * 8;
  const float* Gb  = ws + WS_G + (size_t)b * 4096 + wu * 8;
  float qa[8][2];
#pragma unroll
  for (int m = 0; m < 8; m++) { qa[m][0] = bq[m]; qa[m][1] = bq[m]; }
#pragma unroll 8
  for (int c = 0; c < 64; c++) {
    float2 x = reinterpret_cast<const float2*>(srcb + (size_t)c * NPIX)[lane];
    const float* wr = wq + c * 8;
#pragma unroll
    for (int m = 0; m < 8; m++) {
      float w = wr[m];
      qa[m][0] = fmaf(w, x.x, qa[m][0]);
      qa[m][1] = fmaf(w, x.y, qa[m][1]);
    }
  }
  float s0 = 0.0f, s1 = 0.0f;
#pragma unroll
  for (int m = 0; m < 8; m++) {
    float km = kse[m];
    qa[m][0] = softplus_(qa[m][0]);
    qa[m][1] = softplus_(qa[m][1]);
    s0 = fmaf(qa[m][0], km, s0);
    s1 = fmaf(qa[m][1], km, s1);
  }
  const float r0 = 1.0f / s0, r1 = 1.0f / s1;
#pragma unroll
  for (int m = 0; m < 8; m++) {
    reinterpret_cast<float2*>(&qsL[(wu * 8 + m) * KPX])[lane] =
        make_float2(qa[m][0] * r0, qa[m][1] * r1);
  }
  __syncthreads();
  float acc[8][2];
#pragma unroll
  for (int j = 0; j < 8; j++) { acc[j][0] = bo[wu * 8 + j]; acc[j][1] = acc[j][0]; }
#pragma unroll 8
  for (int pm = 0; pm < 64; pm++) {
    float2 qv = reinterpret_cast<const float2*>(&qsL[pm * KPX])[lane];
    const float* gr = Gb + pm * 64;              // wave-uniform -> s_load
#pragma unroll
    for (int j = 0; j < 8; j++) {
      float g = gr[j];
      acc[j][0] = fmaf(g, qv.x, acc[j][0]);
      acc[j][1] = fmaf(g, qv.y, acc[j][1]);
    }
  }
  float* ob = out + (size_t)(b * 64 + wu * 8) * NPIX + chunk * KPX;
#pragma unroll
  for (int j = 0; j < 8; j++) {
    reinterpret_cast<float2*>(ob + (size_t)j * NPIX)[lane] =
        make_float2(acc[j][0], acc[j][1]);
  }
}

extern "C" void kernel_launch(void* const* d_in, const int* in_sizes, int n_in,
                              void* d_out, int out_size, void* d_ws, size_t ws_size,
                              hipStream_t stream) {
  const float* high    = (const float*)d_in[0];
  const float* low     = (const float*)d_in[1];
  const float* wq_high = (const float*)d_in[2];
  const float* bq_high = (const float*)d_in[3];
  const float* wq_low  = (const float*)d_in[4];
  const float* bq_low  = (const float*)d_in[5];
  const float* wk      = (const float*)d_in[6];
  const float* bk      = (const float*)d_in[7];
  const float* wv      = (const float*)d_in[8];
  const float* bv      = (const float*)d_in[9];
  const float* wo      = (const float*)d_in[10];
  const float* bo      = (const float*)d_in[11];
  float* ws  = (float*)d_ws;
  float* out = (float*)d_out;

  k0_pack<<<1, 256, 0, stream>>>(wq_high, bq_high, wq_low, bq_low, wk, bk, wv, bv, ws);
  dim3 grid1(NCH, NB * 2);
  k1_kv<<<grid1, 256, 0, stream>>>(low, ws, ws + WS_PART);
  k2_g<<<64, 256, 0, stream>>>(ws + WS_PART, wo, ws);
  dim3 grid3(KCH, NB);
  k3_main<<<grid3, 512, 0, stream>>>(high, low, ws, bo, out);
}